// Round 1
// baseline (7803.614 us; speedup 1.0000x reference)
//
#include <hip/hip_runtime.h>
#include <math.h>

#define NBLK 256
#define NTHR 256

typedef float vf4 __attribute__((ext_vector_type(4)));

namespace spinn {

constexpr int Bb = 64, Ss = 48, Hh = 256, TT = 96, Mm = 193, H3 = 768, MLPD = 1024;

// transposed-weight sizes in vf4 units: layout [k4][q][row][4]
constexpr int W4_WIH = 192 * 16 * 64;   // 196608 vf4 (3 MB)   wih  K=768, 64 rows/q
constexpr int W4_WHH = 64 * 16 * 64;    //  65536 vf4 (1 MB)   whh  K=256, 64 rows/q
constexpr int W4_T   = 128 * 16 * 80;   // 163840 vf4 (2.5 MB) [tlw|trw] K=512, 80 rows/q

__device__ __forceinline__ float sigf(float x) { return 1.0f / (1.0f + expf(-x)); }

#define FMA4(acc, a, b)                         \
    {                                           \
        acc.x = fmaf((a).x, (b).x, acc.x);      \
        acc.y = fmaf((a).y, (b).y, acc.y);      \
        acc.z = fmaf((a).z, (b).z, acc.z);      \
        acc.w = fmaf((a).w, (b).w, acc.w);      \
    }

// ---- coherent (device-scope, L1/L2-bypassing) access helpers ----
__device__ __forceinline__ void st_co(float* p, float v) {
    asm volatile("global_store_dword %0, %1, off sc0 sc1" :: "v"(p), "v"(v) : "memory");
}
__device__ __forceinline__ void st_co_v4(vf4* p, vf4 v) {
    asm volatile("global_store_dwordx4 %0, %1, off sc0 sc1" :: "v"(p), "v"(v) : "memory");
}
__device__ __forceinline__ void ld_co_v4_1(const vf4* p0, vf4& r0) {
    asm volatile("global_load_dwordx4 %0, %1, off sc0 sc1\n\t"
                 "s_waitcnt vmcnt(0)"
                 : "=&v"(r0) : "v"(p0) : "memory");
}
__device__ __forceinline__ void ld_co_v4_2(const vf4* p0, const vf4* p1, vf4& r0, vf4& r1) {
    asm volatile("global_load_dwordx4 %0, %2, off sc0 sc1\n\t"
                 "global_load_dwordx4 %1, %3, off sc0 sc1\n\t"
                 "s_waitcnt vmcnt(0)"
                 : "=&v"(r0), "=&v"(r1) : "v"(p0), "v"(p1) : "memory");
}
__device__ __forceinline__ void ld_co_v4_3(const vf4* p0, const vf4* p1, const vf4* p2,
                                           vf4& r0, vf4& r1, vf4& r2) {
    asm volatile("global_load_dwordx4 %0, %3, off sc0 sc1\n\t"
                 "global_load_dwordx4 %1, %4, off sc0 sc1\n\t"
                 "global_load_dwordx4 %2, %5, off sc0 sc1\n\t"
                 "s_waitcnt vmcnt(0)"
                 : "=&v"(r0), "=&v"(r1), "=&v"(r2) : "v"(p0), "v"(p1), "v"(p2) : "memory");
}
__device__ __forceinline__ void ld_co_v4_4(const vf4* p0, const vf4* p1, const vf4* p2, const vf4* p3,
                                           vf4& r0, vf4& r1, vf4& r2, vf4& r3) {
    asm volatile("global_load_dwordx4 %0, %4, off sc0 sc1\n\t"
                 "global_load_dwordx4 %1, %5, off sc0 sc1\n\t"
                 "global_load_dwordx4 %2, %6, off sc0 sc1\n\t"
                 "global_load_dwordx4 %3, %7, off sc0 sc1\n\t"
                 "s_waitcnt vmcnt(0)"
                 : "=&v"(r0), "=&v"(r1), "=&v"(r2), "=&v"(r3)
                 : "v"(p0), "v"(p1), "v"(p2), "v"(p3) : "memory");
}
__device__ __forceinline__ void ld_co_f1x4(const float* p0, const float* p1, const float* p2,
                                           const float* p3, float& r0, float& r1, float& r2, float& r3) {
    asm volatile("global_load_dword %0, %4, off sc0 sc1\n\t"
                 "global_load_dword %1, %5, off sc0 sc1\n\t"
                 "global_load_dword %2, %6, off sc0 sc1\n\t"
                 "global_load_dword %3, %7, off sc0 sc1\n\t"
                 "s_waitcnt vmcnt(0)"
                 : "=&v"(r0), "=&v"(r1), "=&v"(r2), "=&v"(r3)
                 : "v"(p0), "v"(p1), "v"(p2), "v"(p3) : "memory");
}
__device__ __forceinline__ unsigned ld_co_u32(const unsigned* p) {
    unsigned r;
    asm volatile("global_load_dword %0, %1, off sc0 sc1\n\t"
                 "s_waitcnt vmcnt(0)"
                 : "=&v"(r) : "v"(p) : "memory");
    return r;
}

// ---- per-group / grid barrier ----
__device__ __forceinline__ void gbar(unsigned* cnt, unsigned tgt) {
    asm volatile("s_waitcnt vmcnt(0)" ::: "memory");
    __syncthreads();
    if (threadIdx.x == 0) {
        unsigned one = 1u;
        asm volatile("global_atomic_add %0, %1, off" :: "v"(cnt), "v"(one) : "memory");
        while (ld_co_u32(cnt) < tgt) __builtin_amdgcn_s_sleep(1);
    }
    __syncthreads();
}

// ---- wave-level (64-lane) primitives ----
__device__ __forceinline__ float wave_iscan(float v, int lane) {
    #pragma unroll
    for (int off = 1; off < 64; off <<= 1) {
        float u = __shfl_up(v, off, 64);
        if (lane >= off) v += u;
    }
    return v;
}
__device__ __forceinline__ float wred64(float v) {
    #pragma unroll
    for (int off = 1; off < 64; off <<= 1) v += __shfl_xor(v, off, 64);
    return v;
}
__device__ __forceinline__ float wred_ms(float v) {  // reduce over lane bits 4,5
    v += __shfl_xor(v, 16, 64);
    v += __shfl_xor(v, 32, 64);
    return v;
}

}  // namespace spinn

using namespace spinn;

__global__ void __launch_bounds__(NTHR, 1) spinn_kernel(
    const int* __restrict__ x, const float* __restrict__ emb,
    const float* __restrict__ wih, const float* __restrict__ whh,
    const float* __restrict__ bih, const float* __restrict__ bhh,
    const float* __restrict__ aw, const float* __restrict__ ab,
    const float* __restrict__ tlw, const float* __restrict__ tlb,
    const float* __restrict__ trw, const float* __restrict__ trb,
    const float* __restrict__ l0w, const float* __restrict__ l0b,
    const float* __restrict__ l1w, const float* __restrict__ l1b,
    const float* __restrict__ l2w, const float* __restrict__ l2b,
    float* __restrict__ out, float* __restrict__ wsf, unsigned* __restrict__ bar)
{
    const int tid = threadIdx.x;
    const int bid = blockIdx.x;
    const int eg = bid >> 4;          // element group (4 elements)
    const int q  = bid & 15;          // dim slice (16 dims)
    const int e0 = eg * 4;
    const int db = q * 16;

    unsigned* cnt = bar + eg * 32;    // per-group counter, 128B apart
    unsigned barnum = 0;

    // ---- global workspace (floats) ----
    float* XTg  = wsf;                          // [64][768]
    float* Hbg  = XTg + 64 * H3;                // [64][256]
    float* R1g  = Hbg + 64 * Hh;                // [64][256]
    float* R2g  = R1g + 64 * Hh;                // [64][256]
    float* Y0g  = R2g + 64 * Hh;                // [64][1024]
    float* Y1g  = Y0g + 64 * MLPD;              // [64][1024]
    float* Vall = Y1g + 64 * MLPD;
    float* Ball = Vall + (size_t)NBLK * (Mm * 64);
    float* Vg   = Vall + (size_t)bid * (Mm * 64);     // private [193][4 el][16 d]
    float* Bg   = Ball + (size_t)bid * (4 * Ss * 16); // private [4 el][48][16 d]
    // transposed weights (built once per dispatch, shared by all blocks):
    //   layout vf4-index = (k4*16 + q)*ROWS + r  → at fixed k4 a block's 64(80)
    //   rows are CONTIGUOUS → every weight load is a coalesced 1KB wave load.
    float* wihT = Ball + (size_t)NBLK * (4 * Ss * 16);
    float* whhT = wihT + (size_t)W4_WIH * 4;
    float* tTw  = whhT + (size_t)W4_WHH * 4;

    // ---- LDS ----
    __shared__ float s_big[4096];    // union: s_xt[4][768] | s_r12[4][512] | MLP staging
    __shared__ float s_h[1024];      // [4][256] h_{t}
    __shared__ float s_c[64];        // [4][16] private c
    __shared__ float s_g[256];       // [4][4 gates][16]
    __shared__ float s_tg[320];      // [4][5 gates][16]
    __shared__ float s_s[800];       // [4][200] stack strengths
    __shared__ float s_sb[192];      // [4][48] buffer strengths
    __shared__ float sw1[800], sw2[800];
    __shared__ float s_wb[192], s_wbe[192];
    __shared__ float s_wx[16];
    __shared__ float s_xp1[64], s_xp2[64], s_xpb[64];

    float* s_xt = s_big;             // [4][768]

    const int lane = tid & 63;
    const int elw  = tid >> 6;       // wave id == element
    const int ms   = lane >> 4;
    const int dl   = lane & 15;

    // ================= INIT =================
    {
        // --- one-time weight transpose into coalesced [k4][q][row][4] layout ---
        // written coherent (st_co_v4) so other XCDs' plain cached reads see it
        // after the grid barrier below; values identical every dispatch, so any
        // stale L2 lines from a previous dispatch are also correct.
        const int gtid = bid * NTHR + tid;
        const vf4* wih4 = (const vf4*)wih;
        const vf4* whh4 = (const vf4*)whh;
        const vf4* tlw4 = (const vf4*)tlw;
        const vf4* trw4 = (const vf4*)trw;
        for (int o = gtid; o < W4_WIH; o += NBLK * NTHR) {
            int r = o & 63, qq = (o >> 6) & 15, k4 = o >> 10;
            int row = (r >> 4) * Hh + qq * 16 + (r & 15);
            st_co_v4((vf4*)wihT + o, wih4[(size_t)row * 192 + k4]);
        }
        for (int o = gtid; o < W4_WHH; o += NBLK * NTHR) {
            int r = o & 63, qq = (o >> 6) & 15, k4 = o >> 10;
            int row = (r >> 4) * Hh + qq * 16 + (r & 15);
            st_co_v4((vf4*)whhT + o, whh4[(size_t)row * 64 + k4]);
        }
        for (int o = gtid; o < W4_T; o += NBLK * NTHR) {
            int r = o % 80, qq = (o / 80) & 15, k4 = o / 1280;   // rows: 5 gates x 16 d
            int row = (r >> 4) * Hh + qq * 16 + (r & 15);
            vf4 v = (k4 < 64) ? tlw4[(size_t)row * 64 + k4] : trw4[(size_t)row * 64 + (k4 - 64)];
            st_co_v4((vf4*)tTw + o, v);
        }

        // B embedding gather (private), buffer strengths, zero state
        for (int i = tid; i < 4 * Ss * 16; i += NTHR) {
            int el = i / (Ss * 16);
            int rem = i - el * (Ss * 16);
            int s = rem >> 4, d = rem & 15;
            int tok = x[(e0 + el) * Ss + s];
            Bg[i] = emb[(size_t)tok * Hh + db + d];
        }
        if (tid < 4 * Ss) {
            int el = tid / Ss, s = tid % Ss;
            s_sb[tid] = (x[(e0 + el) * Ss + s] > 0) ? 1.0f : 0.0f;
        }
        for (int i = tid; i < 800; i += NTHR) s_s[i] = 0.0f;
        for (int i = tid; i < 1024; i += NTHR) s_h[i] = 0.0f;
        if (tid < 64) s_c[tid] = 0.0f;
        for (int i = tid; i < Mm * 64; i += NTHR) Vg[i] = 0.0f;
        asm volatile("s_waitcnt vmcnt(0)" ::: "memory");
        __syncthreads();
        // initial x_b = read_buffer(ones); x1 = x2 = 0
        float sbv = (lane < Ss) ? s_sb[elw * Ss + lane] : 0.0f;
        float P = wave_iscan(sbv, lane);
        float wbe = fminf(P, 1.0f) - fminf(P - sbv, 1.0f);
        if (lane < Ss) s_wbe[elw * Ss + lane] = wbe;
        float axb = 0.0f;
        for (int t2 = ms * 12; t2 < ms * 12 + 12; t2++)
            axb = fmaf(s_wbe[elw * Ss + t2], Bg[elw * (Ss * 16) + t2 * 16 + dl], axb);
        axb = wred_ms(axb);
        if (lane < 16) {
            float* xte = XTg + (size_t)(e0 + elw) * H3;
            st_co(xte + db + dl, axb);
            st_co(xte + 256 + db + dl, 0.0f);
            st_co(xte + 512 + db + dl, 0.0f);
        }
    }
    // grid-wide barrier: publishes transposed weights AND initial XT
    gbar(bar + 512, (unsigned)NBLK);

    // ================= time loop =================
    for (int t = 0; t < TT; t++) {
        const int idx  = 191 - 2 * t;
        const int idx2 = idx - 1;

        // ---------- Phase L: LSTM ----------
        {
            const vf4* src = (const vf4*)XTg + (size_t)e0 * 192;
            vf4 a, b, c;
            ld_co_v4_3(src + tid, src + tid + 256, src + tid + 512, a, b, c);
            vf4* sx4 = (vf4*)s_xt;
            sx4[tid] = a; sx4[tid + 256] = b; sx4[tid + 512] = c;
            __syncthreads();
            // gate dots via transposed weights: coalesced 1KB loads, L1-broadcast
            // across the 4 element-waves (same addresses).
            int r = tid & 63;
            int row = (r >> 4) * Hh + db + (r & 15);
            const vf4* w4  = (const vf4*)wihT + (size_t)q * 64 + r;   // +k*1024
            const vf4* x4  = (const vf4*)s_xt + elw * 192;
            const vf4* wh4 = (const vf4*)whhT + (size_t)q * 64 + r;   // +k*1024
            const vf4* h4  = (const vf4*)s_h + elw * 64;
            vf4 acc4 = {0.f, 0.f, 0.f, 0.f};
            #pragma unroll 16
            for (int k = 0; k < 192; k++) { vf4 wv = w4[(size_t)k << 10], xv = x4[k]; FMA4(acc4, wv, xv); }
            #pragma unroll 16
            for (int k = 0; k < 64; k++)  { vf4 wv = wh4[(size_t)k << 10], hv = h4[k]; FMA4(acc4, wv, hv); }
            s_g[elw * 64 + r] = bih[row] + bhh[row] + acc4.x + acc4.y + acc4.z + acc4.w;
            __syncthreads();
            if (tid < 64) {
                int el2 = tid >> 4, d2 = tid & 15;
                float gi = s_g[el2 * 64 + d2], gf = s_g[el2 * 64 + 16 + d2];
                float gg = s_g[el2 * 64 + 32 + d2], go = s_g[el2 * 64 + 48 + d2];
                float cv = sigf(gf) * s_c[tid] + sigf(gi) * tanhf(gg);
                s_c[tid] = cv;
                float hv = sigf(go) * tanhf(cv);
                st_co(Hbg + (size_t)(e0 + el2) * Hh + db + d2, hv);
            }
        }
        gbar(cnt, ++barnum * 16);

        // ---------- Phase T1 (fully per-wave; wave = element) ----------
        {
            const int e = e0 + elw;
            float h0, h1, h2, h3;
            const float* hb = Hbg + (size_t)e * Hh + lane;
            ld_co_f1x4(hb, hb + 64, hb + 128, hb + 192, h0, h1, h2, h3);
            s_h[elw * Hh + lane] = h0;       s_h[elw * Hh + 64 + lane] = h1;
            s_h[elw * Hh + 128 + lane] = h2; s_h[elw * Hh + 192 + lane] = h3;
            float lg0 = h0 * aw[lane] + h1 * aw[64 + lane] + h2 * aw[128 + lane] + h3 * aw[192 + lane];
            float lg1 = h0 * aw[256 + lane] + h1 * aw[320 + lane] + h2 * aw[384 + lane] + h3 * aw[448 + lane];
            lg0 = wred64(lg0) + ab[0];
            lg1 = wred64(lg1) + ab[1];
            float a_r = 1.0f / (1.0f + expf(10.0f * (lg1 - lg0)));
            float a_s = 1.0f / (1.0f + expf(10.0f * (lg0 - lg1)));
            // pop scan over s (4 m per lane)
            int m0 = lane * 4;
            float v0 = (m0     < Mm) ? s_s[elw * 200 + m0]     : 0.0f;
            float v1 = (m0 + 1 < Mm) ? s_s[elw * 200 + m0 + 1] : 0.0f;
            float v2 = (m0 + 2 < Mm) ? s_s[elw * 200 + m0 + 2] : 0.0f;
            float v3 = (m0 + 3 < Mm) ? s_s[elw * 200 + m0 + 3] : 0.0f;
            float c1 = v0 + v1, c2 = c1 + v2, c3 = c2 + v3;
            float inc = c3;
            #pragma unroll
            for (int off = 1; off < 64; off <<= 1) {
                float u = __shfl_up(inc, off, 64);
                if (lane >= off) inc += u;
            }
            float ex = inc - c3;
            float Pv[4]  = {ex + v0, ex + c1, ex + c2, ex + c3};
            float Pp[4]  = {ex, ex + v0, ex + c1, ex + c2};
            float vv_[4] = {v0, v1, v2, v3};
            float sn[4];
            #pragma unroll
            for (int i = 0; i < 4; i++) {
                int m = m0 + i;
                float w1 = fminf(Pv[i], a_r) - fminf(Pp[i], a_r);
                float wt = fminf(Pv[i], 1.0f + a_r) - fminf(Pp[i], 1.0f + a_r);
                float s2 = vv_[i] - wt;
                if (m == idx) s2 = a_r;
                if (m == idx2) s2 = a_s;
                sn[i] = s2;
                if (m < Mm) {
                    sw1[elw * 200 + m] = w1;
                    sw2[elw * 200 + m] = wt - w1;
                    s_s[elw * 200 + m] = s2;
                }
            }
            // r1/r2 dots (lane = ms*16+dl, m-split by ms)
            int mA = ms * 48, mB = (ms == 3) ? Mm : (mA + 48);
            float a1 = 0.0f, a2 = 0.0f;
            for (int m = mA; m < mB; m++) {
                float vv = Vg[m * 64 + elw * 16 + dl];
                a1 = fmaf(sw1[elw * 200 + m], vv, a1);
                a2 = fmaf(sw2[elw * 200 + m], vv, a2);
            }
            a1 = wred_ms(a1); a2 = wred_ms(a2);
            if (lane < 16) {
                st_co(R1g + (size_t)e * Hh + db + dl, a1);
                st_co(R2g + (size_t)e * Hh + db + dl, a2);
            }
            // push scan (alpha = 1) on updated s
            float d1 = sn[0] + sn[1], d2 = d1 + sn[2], d3 = d2 + sn[3];
            float inc2 = d3;
            #pragma unroll
            for (int off = 1; off < 64; off <<= 1) {
                float u = __shfl_up(inc2, off, 64);
                if (lane >= off) inc2 += u;
            }
            float ex2 = inc2 - d3;
            float Qv[4] = {ex2 + sn[0], ex2 + d1, ex2 + d2, ex2 + d3};
            float Qp[4] = {ex2, ex2 + sn[0], ex2 + d1, ex2 + d2};
            #pragma unroll
            for (int i = 0; i < 4; i++) {
                int m = m0 + i;
                float w1e = fminf(Qv[i], 1.0f) - fminf(Qp[i], 1.0f);
                float w2e = (fminf(Qv[i], 2.0f) - fminf(Qp[i], 2.0f)) - w1e;
                if (m == idx)  { s_wx[elw * 4 + 0] = w1e; s_wx[elw * 4 + 1] = w2e; w1e = 0.0f; w2e = 0.0f; }
                if (m == idx2) { s_wx[elw * 4 + 2] = w1e; s_wx[elw * 4 + 3] = w2e; w1e = 0.0f; w2e = 0.0f; }
                if (m < Mm) { sw1[elw * 200 + m] = w1e; sw2[elw * 200 + m] = w2e; }
            }
            // buffer pop + push scans
            float sbv = (lane < Ss) ? s_sb[elw * Ss + lane] : 0.0f;
            float Pb = wave_iscan(sbv, lane);
            float wb = fminf(Pb, a_s) - fminf(Pb - sbv, a_s);
            float sbn = sbv - wb;
            float Pb2 = wave_iscan(sbn, lane);
            float wbe = fminf(Pb2, 1.0f) - fminf(Pb2 - sbn, 1.0f);
            if (lane < Ss) {
                s_sb[elw * Ss + lane] = sbn;
                s_wb[elw * Ss + lane] = wb;
                s_wbe[elw * Ss + lane] = wbe;
            }
            // buf (V[idx2]) and xb dots
            float abf = 0.0f, axb = 0.0f;
            for (int t2 = ms * 12; t2 < ms * 12 + 12; t2++) {
                float be = Bg[elw * (Ss * 16) + t2 * 16 + dl];
                abf = fmaf(s_wb[elw * Ss + t2], be, abf);
                axb = fmaf(s_wbe[elw * Ss + t2], be, axb);
            }
            abf = wred_ms(abf); axb = wred_ms(axb);
            if (lane < 16) Vg[idx2 * 64 + elw * 16 + dl] = abf;
            // x1/x2 partial dots
            float x1 = 0.0f, x2 = 0.0f;
            for (int m = mA; m < mB; m++) {
                float vv = Vg[m * 64 + elw * 16 + dl];
                x1 = fmaf(sw1[elw * 200 + m], vv, x1);
                x2 = fmaf(sw2[elw * 200 + m], vv, x2);
            }
            if (ms == 0) {
                x1 = fmaf(s_wx[elw * 4 + 2], abf, x1);
                x2 = fmaf(s_wx[elw * 4 + 3], abf, x2);
            }
            x1 = wred_ms(x1); x2 = wred_ms(x2);
            if (lane < 16) {
                s_xp1[elw * 16 + dl] = x1;
                s_xp2[elw * 16 + dl] = x2;
                s_xpb[elw * 16 + dl] = axb;
            }
        }
        gbar(cnt, ++barnum * 16);

        // ---------- Phase T2: tree cell + finish xt ----------
        {
            const vf4* pR1 = (const vf4*)R1g + (size_t)e0 * 64 + tid;
            const vf4* pR2 = (const vf4*)R2g + (size_t)e0 * 64 + tid;
            vf4 ra, rb;
            ld_co_v4_2(pR1, pR2, ra, rb);
            vf4* sr = (vf4*)s_big;               // [4][128] vf4 = [r1|r2] per element
            sr[elw * 128 + (tid & 63)] = ra;
            sr[elw * 128 + 64 + (tid & 63)] = rb;
            __syncthreads();
            // tree dots, pass1: gates 0..3 via transposed concat weights
            {
                int r = tid & 63;
                int row = (r >> 4) * Hh + db + (r & 15);
                const vf4* w  = (const vf4*)tTw + (size_t)q * 80 + r;   // +k*1280
                const vf4* xx = (const vf4*)s_big + elw * 128;
                vf4 acc4 = {0.f, 0.f, 0.f, 0.f};
                #pragma unroll 16
                for (int k = 0; k < 128; k++) { vf4 wv = w[(size_t)k * 1280], xv = xx[k]; FMA4(acc4, wv, xv); }
                s_tg[elw * 80 + r] = tlb[row] + trb[row] + acc4.x + acc4.y + acc4.z + acc4.w;
            }
            // pass2: gate 4 (output gate)
            if (tid < 64) {
                int el2 = tid >> 4, d2 = tid & 15;
                int row = 4 * Hh + db + d2;
                const vf4* w  = (const vf4*)tTw + (size_t)q * 80 + 64 + d2;
                const vf4* xx = (const vf4*)s_big + el2 * 128;
                vf4 acc4 = {0.f, 0.f, 0.f, 0.f};
                #pragma unroll 16
                for (int k = 0; k < 128; k++) { vf4 wv = w[(size_t)k * 1280], xv = xx[k]; FMA4(acc4, wv, xv); }
                s_tg[el2 * 80 + 64 + d2] = tlb[row] + trb[row] + acc4.x + acc4.y + acc4.z + acc4.w;
            }
            __syncthreads();
            if (tid < 64) {
                int el2 = tid >> 4, d2 = tid & 15;
                int e = e0 + el2;
                float ta  = s_tg[el2 * 80 + d2];
                float ti  = s_tg[el2 * 80 + 16 + d2];
                float tf1 = s_tg[el2 * 80 + 32 + d2];
                float tf2 = s_tg[el2 * 80 + 48 + d2];
                float to  = s_tg[el2 * 80 + 64 + d2];
                float r1d = s_big[el2 * 512 + db + d2];
                float r2d = s_big[el2 * 512 + 256 + db + d2];
                float ct = tanhf(ta) * sigf(ti) + sigf(tf1) * r1d + sigf(tf2) * r2d;
                float ht = sigf(to) * tanhf(ct);
                Vg[idx * 64 + el2 * 16 + d2] = ht;
                float x1f = fmaf(s_wx[el2 * 4 + 0], ht, s_xp1[tid]);
                float x2f = fmaf(s_wx[el2 * 4 + 1], ht, s_xp2[tid]);
                float* xte = XTg + (size_t)e * H3;
                st_co(xte + db + d2, s_xpb[tid]);
                st_co(xte + 256 + db + d2, x1f);
                st_co(xte + 512 + db + d2, x2f);
            }
        }
        gbar(cnt, ++barnum * 16);
    }

    // ================= MLP head =================
    {   // layer 0: input = XT[:, 256:512]
        int j = tid & 63;
        const vf4* px = (const vf4*)XTg + (size_t)(e0 + elw) * 192 + 64 + j;
        vf4 xv;
        ld_co_v4_1(px, xv);
        ((vf4*)s_big)[elw * 64 + j] = xv;
        __syncthreads();
        int row = q * 64 + (tid & 63);
        const vf4* w = (const vf4*)l0w + (size_t)row * 64;
        const vf4* xx = (const vf4*)s_big + elw * 64;
        vf4 acc4 = {0.f, 0.f, 0.f, 0.f};
        #pragma unroll 4
        for (int k = 0; k < 64; k++) { vf4 wv = w[k], v = xx[k]; FMA4(acc4, wv, v); }
        float y = fmaxf(l0b[row] + acc4.x + acc4.y + acc4.z + acc4.w, 0.0f);
        st_co(Y0g + (size_t)(e0 + elw) * MLPD + row, y);
    }
    gbar(cnt, ++barnum * 16);
    {   // layer 1
        const vf4* p = (const vf4*)Y0g + (size_t)e0 * 256;
        vf4 y0, y1, y2, y3;
        ld_co_v4_4(p + tid, p + tid + 256, p + tid + 512, p + tid + 768, y0, y1, y2, y3);
        vf4* sy = (vf4*)s_big;
        sy[tid] = y0; sy[tid + 256] = y1; sy[tid + 512] = y2; sy[tid + 768] = y3;
        __syncthreads();
        int row = q * 64 + (tid & 63);
        const vf4* w = (const vf4*)l1w + (size_t)row * 256;
        const vf4* yy = sy + elw * 256;
        vf4 acc4 = {0.f, 0.f, 0.f, 0.f};
        #pragma unroll 4
        for (int k = 0; k < 256; k++) { vf4 wv = w[k], v = yy[k]; FMA4(acc4, wv, v); }
        float y = fmaxf(l1b[row] + acc4.x + acc4.y + acc4.z + acc4.w, 0.0f);
        st_co(Y1g + (size_t)(e0 + elw) * MLPD + row, y);
    }
    gbar(cnt, ++barnum * 16);
    if (q < 4) {  // layer 2: block (eg, q=el) handles element e0+q
        int e = e0 + q;
        const vf4* p = (const vf4*)Y1g + (size_t)e * 256 + tid;
        vf4 yv;
        ld_co_v4_1(p, yv);
        #pragma unroll
        for (int r = 0; r < 3; r++) {
            const float* w = l2w + (size_t)r * MLPD + tid * 4;
            s_h[r * 256 + tid] = yv.x * w[0] + yv.y * w[1] + yv.z * w[2] + yv.w * w[3];
        }
        __syncthreads();
        for (int off = 128; off >= 1; off >>= 1) {
            if (tid < off) {
                #pragma unroll
                for (int r = 0; r < 3; r++)
                    s_h[r * 256 + tid] += s_h[r * 256 + tid + off];
            }
            __syncthreads();
        }
        if (tid < 3) out[e * 3 + tid] = s_h[tid * 256] + l2b[tid];
    }
}

extern "C" void kernel_launch(void* const* d_in, const int* in_sizes, int n_in,
                              void* d_out, int out_size, void* d_ws, size_t ws_size,
                              hipStream_t stream) {
    (void)in_sizes; (void)n_in; (void)out_size; (void)ws_size;
    (void)hipMemsetAsync(d_ws, 0, 4096, stream);  // barrier counters (group + grid)

    const int*   x_   = (const int*)d_in[0];
    const float* emb  = (const float*)d_in[1];
    const float* wih  = (const float*)d_in[2];
    const float* whh  = (const float*)d_in[3];
    const float* bih  = (const float*)d_in[4];
    const float* bhh  = (const float*)d_in[5];
    const float* aw   = (const float*)d_in[6];
    const float* ab   = (const float*)d_in[7];
    const float* tlw  = (const float*)d_in[8];
    const float* tlb  = (const float*)d_in[9];
    const float* trw  = (const float*)d_in[10];
    const float* trb  = (const float*)d_in[11];
    const float* l0w  = (const float*)d_in[12];
    const float* l0b  = (const float*)d_in[13];
    const float* l1w  = (const float*)d_in[14];
    const float* l1b  = (const float*)d_in[15];
    const float* l2w  = (const float*)d_in[16];
    const float* l2b  = (const float*)d_in[17];

    float* wsf = (float*)((char*)d_ws + 4096);
    unsigned* bar = (unsigned*)d_ws;

    spinn_kernel<<<dim3(NBLK), dim3(NTHR), 0, stream>>>(
        x_, emb, wih, whh, bih, bhh, aw, ab, tlw, tlb, trw, trb,
        l0w, l0b, l1w, l1b, l2w, l2b, (float*)d_out, wsf, bar);
}

// Round 3
// 6782.521 us; speedup vs baseline: 1.1505x; 1.1505x over previous
//
#include <hip/hip_runtime.h>
#include <math.h>

#define NBLK 256
#define NTHR 256

typedef float vf4 __attribute__((ext_vector_type(4)));

namespace spinn {

constexpr int Bb = 64, Ss = 48, Hh = 256, TT = 96, Mm = 193, H3 = 768, MLPD = 1024;
constexpr int Mp = 196;   // padded stack rows (4 ms-groups x 49)

__device__ __forceinline__ float sigf(float x) { return 1.0f / (1.0f + expf(-x)); }

#define FMA4(acc, a, b)                         \
    {                                           \
        acc.x = fmaf((a).x, (b).x, acc.x);      \
        acc.y = fmaf((a).y, (b).y, acc.y);      \
        acc.z = fmaf((a).z, (b).z, acc.z);      \
        acc.w = fmaf((a).w, (b).w, acc.w);      \
    }

// ---- coherent (device-scope) access helpers ----
__device__ __forceinline__ void st_co(float* p, float v) {
    asm volatile("global_store_dword %0, %1, off sc0 sc1" :: "v"(p), "v"(v) : "memory");
}
__device__ __forceinline__ void ld_co_v4_1(const vf4* p0, vf4& r0) {
    asm volatile("global_load_dwordx4 %0, %1, off sc0 sc1\n\t"
                 "s_waitcnt vmcnt(0)"
                 : "=&v"(r0) : "v"(p0) : "memory");
}
__device__ __forceinline__ void ld_co_v4_2(const vf4* p0, const vf4* p1, vf4& r0, vf4& r1) {
    asm volatile("global_load_dwordx4 %0, %2, off sc0 sc1\n\t"
                 "global_load_dwordx4 %1, %3, off sc0 sc1\n\t"
                 "s_waitcnt vmcnt(0)"
                 : "=&v"(r0), "=&v"(r1) : "v"(p0), "v"(p1) : "memory");
}
__device__ __forceinline__ void ld_co_v4_3(const vf4* p0, const vf4* p1, const vf4* p2,
                                           vf4& r0, vf4& r1, vf4& r2) {
    asm volatile("global_load_dwordx4 %0, %3, off sc0 sc1\n\t"
                 "global_load_dwordx4 %1, %4, off sc0 sc1\n\t"
                 "global_load_dwordx4 %2, %5, off sc0 sc1\n\t"
                 "s_waitcnt vmcnt(0)"
                 : "=&v"(r0), "=&v"(r1), "=&v"(r2) : "v"(p0), "v"(p1), "v"(p2) : "memory");
}
__device__ __forceinline__ void ld_co_v4_4(const vf4* p0, const vf4* p1, const vf4* p2, const vf4* p3,
                                           vf4& r0, vf4& r1, vf4& r2, vf4& r3) {
    asm volatile("global_load_dwordx4 %0, %4, off sc0 sc1\n\t"
                 "global_load_dwordx4 %1, %5, off sc0 sc1\n\t"
                 "global_load_dwordx4 %2, %6, off sc0 sc1\n\t"
                 "global_load_dwordx4 %3, %7, off sc0 sc1\n\t"
                 "s_waitcnt vmcnt(0)"
                 : "=&v"(r0), "=&v"(r1), "=&v"(r2), "=&v"(r3)
                 : "v"(p0), "v"(p1), "v"(p2), "v"(p3) : "memory");
}
__device__ __forceinline__ void ld_co_f1x4(const float* p0, const float* p1, const float* p2,
                                           const float* p3, float& r0, float& r1, float& r2, float& r3) {
    asm volatile("global_load_dword %0, %4, off sc0 sc1\n\t"
                 "global_load_dword %1, %5, off sc0 sc1\n\t"
                 "global_load_dword %2, %6, off sc0 sc1\n\t"
                 "global_load_dword %3, %7, off sc0 sc1\n\t"
                 "s_waitcnt vmcnt(0)"
                 : "=&v"(r0), "=&v"(r1), "=&v"(r2), "=&v"(r3)
                 : "v"(p0), "v"(p1), "v"(p2), "v"(p3) : "memory");
}
__device__ __forceinline__ void ld_co_f2(const float* p0, const float* p1, float& r0, float& r1) {
    asm volatile("global_load_dword %0, %2, off sc0 sc1\n\t"
                 "global_load_dword %1, %3, off sc0 sc1\n\t"
                 "s_waitcnt vmcnt(0)"
                 : "=&v"(r0), "=&v"(r1) : "v"(p0), "v"(p1) : "memory");
}
__device__ __forceinline__ unsigned ld_co_u32(const unsigned* p) {
    unsigned r;
    asm volatile("global_load_dword %0, %1, off sc0 sc1\n\t"
                 "s_waitcnt vmcnt(0)"
                 : "=&v"(r) : "v"(p) : "memory");
    return r;
}

// ---- per-group (16-block) barrier ----
__device__ __forceinline__ void gbar(unsigned* cnt, unsigned tgt) {
    asm volatile("s_waitcnt vmcnt(0)" ::: "memory");
    __syncthreads();
    if (threadIdx.x == 0) {
        unsigned one = 1u;
        asm volatile("global_atomic_add %0, %1, off" :: "v"(cnt), "v"(one) : "memory");
        while (ld_co_u32(cnt) < tgt) __builtin_amdgcn_s_sleep(1);
    }
    __syncthreads();
}

// ---- wave-level (64-lane) primitives ----
__device__ __forceinline__ float wave_iscan(float v, int lane) {
    #pragma unroll
    for (int off = 1; off < 64; off <<= 1) {
        float u = __shfl_up(v, off, 64);
        if (lane >= off) v += u;
    }
    return v;
}
__device__ __forceinline__ float wred64(float v) {
    #pragma unroll
    for (int off = 1; off < 64; off <<= 1) v += __shfl_xor(v, off, 64);
    return v;
}
__device__ __forceinline__ float wred_ms(float v) {  // reduce over lane bits 4,5
    v += __shfl_xor(v, 16, 64);
    v += __shfl_xor(v, 32, 64);
    return v;
}

}  // namespace spinn

using namespace spinn;

__global__ void __launch_bounds__(NTHR, 1) spinn_kernel(
    const int* __restrict__ x, const float* __restrict__ emb,
    const float* __restrict__ wih, const float* __restrict__ whh,
    const float* __restrict__ bih, const float* __restrict__ bhh,
    const float* __restrict__ aw, const float* __restrict__ ab,
    const float* __restrict__ tlw, const float* __restrict__ tlb,
    const float* __restrict__ trw, const float* __restrict__ trb,
    const float* __restrict__ l0w, const float* __restrict__ l0b,
    const float* __restrict__ l1w, const float* __restrict__ l1b,
    const float* __restrict__ l2w, const float* __restrict__ l2b,
    float* __restrict__ out, float* __restrict__ wsf, unsigned* __restrict__ bar)
{
    const int tid = threadIdx.x;
    const int bid = blockIdx.x;
    const int eg = bid >> 4;          // element group (4 elements)
    const int q  = bid & 15;          // dim slice (16 dims)
    const int e0 = eg * 4;
    const int db = q * 16;

    unsigned* cnt = bar + eg * 32;    // per-group counter, 128B apart
    unsigned barnum = 0;

    // ---- global workspace (floats) ----
    float* XTg  = wsf;                          // [64][768]
    float* Hbg  = XTg + 64 * H3;                // [64][256]
    float* R1g  = Hbg + 64 * Hh;                // [64][256]
    float* R2g  = R1g + 64 * Hh;                // [64][256]
    float* Y0g  = R2g + 64 * Hh;                // [64][1024]
    float* Y1g  = Y0g + 64 * MLPD;              // [64][1024]
    float* Vall = Y1g + 64 * MLPD;
    float* Vg   = Vall + (size_t)bid * (Mp * 64);  // private [196][4 el][16 d]

    // ---- LDS (all small; no weight staging) ----
    __shared__ float s_h[1024];      // [4][256] h_t (written T1, used next L; l2 reuses)
    __shared__ float s_c[64];        // [4][16]
    __shared__ float s_g[256];       // [4][4 gates][16]
    __shared__ float s_tg[320];      // [4][5 gates][16]
    __shared__ float s_s[832];       // [4][208] stack strengths (padded)
    __shared__ float s_sb[192];      // [4][48]
    __shared__ float sw1[832], sw2[832];   // pop weights
    __shared__ float pw1[832], pw2[832];   // push weights
    __shared__ float s_wb[192], s_wbe[192];
    __shared__ float s_wx[16];
    __shared__ float s_xp1[64], s_xp2[64], s_xpb[64];
    __shared__ float s_bias[64];     // bih+bhh for this q's 64 LSTM rows
    __shared__ float s_tbias[80];    // tlb+trb for this q's 80 tree rows
    __shared__ float s_B[4 * Ss * 17]; // [4 el][48][16+pad]

    const int lane = tid & 63;
    const int elw  = tid >> 6;       // wave id == element
    const int ms   = lane >> 4;
    const int dl   = lane & 15;

    // ================= INIT =================
    {
        for (int i = tid; i < 4 * Ss * 16; i += NTHR) {
            int el = i / (Ss * 16);
            int rem = i - el * (Ss * 16);
            int s = rem >> 4, d = rem & 15;
            int tok = x[(e0 + el) * Ss + s];
            s_B[(el * Ss + s) * 17 + d] = emb[(size_t)tok * Hh + db + d];
        }
        if (tid < 4 * Ss) {
            int el = tid / Ss, s = tid % Ss;
            s_sb[tid] = (x[(e0 + el) * Ss + s] > 0) ? 1.0f : 0.0f;
        }
        for (int i = tid; i < 832; i += NTHR) s_s[i] = 0.0f;
        for (int i = tid; i < 1024; i += NTHR) s_h[i] = 0.0f;
        if (tid < 64) s_c[tid] = 0.0f;
        if (tid < 64) {
            int row = (tid >> 4) * Hh + db + (tid & 15);
            s_bias[tid] = bih[row] + bhh[row];
        }
        if (tid < 80) {
            int row = (tid >> 4) * Hh + db + (tid & 15);
            s_tbias[tid] = tlb[row] + trb[row];
        }
        for (int i = tid; i < Mp * 64; i += NTHR) Vg[i] = 0.0f;
        asm volatile("s_waitcnt vmcnt(0)" ::: "memory");
        __syncthreads();
        // initial x_b = read_buffer(ones); x1 = x2 = 0
        float sbv = (lane < Ss) ? s_sb[elw * Ss + lane] : 0.0f;
        float P = wave_iscan(sbv, lane);
        float wbe = fminf(P, 1.0f) - fminf(P - sbv, 1.0f);
        if (lane < Ss) s_wbe[elw * Ss + lane] = wbe;
        float axb = 0.0f;
        #pragma unroll
        for (int j = 0; j < 12; j++) {
            int s = ms * 12 + j;
            axb = fmaf(s_wbe[elw * Ss + s], s_B[(elw * Ss + s) * 17 + dl], axb);
        }
        axb = wred_ms(axb);
        if (lane < 16) {
            float* xte = XTg + (size_t)(e0 + elw) * H3;
            st_co(xte + db + dl, axb);
            st_co(xte + 256 + db + dl, 0.0f);
            st_co(xte + 512 + db + dl, 0.0f);
        }
    }
    gbar(cnt, ++barnum * 16);

    // ================= time loop =================
    for (int t = 0; t < TT; t++) {
        const int idx  = 191 - 2 * t;
        const int idx2 = idx - 1;

        // ---------- Phase L: LSTM (wave-per-row coalesced dots) ----------
        {
            const int e = e0 + elw;
            const vf4* xb4 = (const vf4*)XTg + (size_t)e * 192;
            vf4 xr0, xr1, xr2;
            ld_co_v4_3(xb4 + lane, xb4 + 64 + lane, xb4 + 128 + lane, xr0, xr1, xr2);
            vf4 hr = ((const vf4*)s_h)[elw * 64 + lane];
            #pragma unroll 4
            for (int r = 0; r < 64; r++) {
                int row = ((r >> 4) << 8) + db + (r & 15);   // g*256 + db + d
                const vf4* w  = (const vf4*)wih + (size_t)row * 192;
                const vf4* wh = (const vf4*)whh + (size_t)row * 64;
                vf4 w0 = w[lane], w1 = w[64 + lane], w2 = w[128 + lane], w3 = wh[lane];
                vf4 acc = {0.f, 0.f, 0.f, 0.f};
                FMA4(acc, w0, xr0); FMA4(acc, w1, xr1);
                FMA4(acc, w2, xr2); FMA4(acc, w3, hr);
                float sv = wred64(acc.x + acc.y + acc.z + acc.w);
                if (lane == 0) s_g[elw * 64 + r] = sv + s_bias[r];
            }
            __syncthreads();
            if (tid < 64) {
                int el2 = tid >> 4, d2 = tid & 15;
                float gi = s_g[el2 * 64 + d2], gf = s_g[el2 * 64 + 16 + d2];
                float gg = s_g[el2 * 64 + 32 + d2], go = s_g[el2 * 64 + 48 + d2];
                float cv = sigf(gf) * s_c[tid] + sigf(gi) * tanhf(gg);
                s_c[tid] = cv;
                float hv = sigf(go) * tanhf(cv);
                st_co(Hbg + (size_t)(e0 + el2) * Hh + db + d2, hv);
            }
        }
        gbar(cnt, ++barnum * 16);

        // ---------- Phase T1 (per-wave; wave = element) ----------
        {
            const int e = e0 + elw;
            float h0, h1, h2, h3;
            const float* hb = Hbg + (size_t)e * Hh + lane;
            ld_co_f1x4(hb, hb + 64, hb + 128, hb + 192, h0, h1, h2, h3);
            s_h[elw * Hh + lane] = h0;       s_h[elw * Hh + 64 + lane] = h1;
            s_h[elw * Hh + 128 + lane] = h2; s_h[elw * Hh + 192 + lane] = h3;
            float lg0 = h0 * aw[lane] + h1 * aw[64 + lane] + h2 * aw[128 + lane] + h3 * aw[192 + lane];
            float lg1 = h0 * aw[256 + lane] + h1 * aw[320 + lane] + h2 * aw[384 + lane] + h3 * aw[448 + lane];
            lg0 = wred64(lg0) + ab[0];
            lg1 = wred64(lg1) + ab[1];
            float a_r = 1.0f / (1.0f + expf(10.0f * (lg1 - lg0)));
            float a_s = 1.0f / (1.0f + expf(10.0f * (lg0 - lg1)));
            // pop scan over s (4 m per lane)
            int m0 = lane * 4;
            float v0 = (m0     < Mm) ? s_s[elw * 208 + m0]     : 0.0f;
            float v1 = (m0 + 1 < Mm) ? s_s[elw * 208 + m0 + 1] : 0.0f;
            float v2 = (m0 + 2 < Mm) ? s_s[elw * 208 + m0 + 2] : 0.0f;
            float v3 = (m0 + 3 < Mm) ? s_s[elw * 208 + m0 + 3] : 0.0f;
            float c1 = v0 + v1, c2 = c1 + v2, c3 = c2 + v3;
            float inc = c3;
            #pragma unroll
            for (int off = 1; off < 64; off <<= 1) {
                float u = __shfl_up(inc, off, 64);
                if (lane >= off) inc += u;
            }
            float ex = inc - c3;
            float Pv[4]  = {ex + v0, ex + c1, ex + c2, ex + c3};
            float Pp[4]  = {ex, ex + v0, ex + c1, ex + c2};
            float vv_[4] = {v0, v1, v2, v3};
            float sn[4];
            #pragma unroll
            for (int i = 0; i < 4; i++) {
                int m = m0 + i;
                float w1 = fminf(Pv[i], a_r) - fminf(Pp[i], a_r);
                float wt = fminf(Pv[i], 1.0f + a_r) - fminf(Pp[i], 1.0f + a_r);
                float s2 = vv_[i] - wt;
                if (m == idx) s2 = a_r;
                if (m == idx2) s2 = a_s;
                sn[i] = s2;
                if (m < Mm) {
                    sw1[elw * 208 + m] = w1;
                    sw2[elw * 208 + m] = wt - w1;
                    s_s[elw * 208 + m] = s2;
                } else if (m < Mp) {
                    sw1[elw * 208 + m] = 0.0f;
                    sw2[elw * 208 + m] = 0.0f;
                }
            }
            // push scan (alpha = 1) on updated s (values in sn registers)
            float d1 = sn[0] + sn[1], d2 = d1 + sn[2], d3 = d2 + sn[3];
            float inc2 = d3;
            #pragma unroll
            for (int off = 1; off < 64; off <<= 1) {
                float u = __shfl_up(inc2, off, 64);
                if (lane >= off) inc2 += u;
            }
            float ex2 = inc2 - d3;
            float Qv[4] = {ex2 + sn[0], ex2 + d1, ex2 + d2, ex2 + d3};
            float Qp[4] = {ex2, ex2 + sn[0], ex2 + d1, ex2 + d2};
            #pragma unroll
            for (int i = 0; i < 4; i++) {
                int m = m0 + i;
                float w1e = fminf(Qv[i], 1.0f) - fminf(Qp[i], 1.0f);
                float w2e = (fminf(Qv[i], 2.0f) - fminf(Qp[i], 2.0f)) - w1e;
                if (m == idx)  { s_wx[elw * 4 + 0] = w1e; s_wx[elw * 4 + 1] = w2e; w1e = 0.0f; w2e = 0.0f; }
                if (m == idx2) { s_wx[elw * 4 + 2] = w1e; s_wx[elw * 4 + 3] = w2e; w1e = 0.0f; w2e = 0.0f; }
                if (m < Mm) {
                    pw1[elw * 208 + m] = w1e;
                    pw2[elw * 208 + m] = w2e;
                } else if (m < Mp) {
                    pw1[elw * 208 + m] = 0.0f;
                    pw2[elw * 208 + m] = 0.0f;
                }
            }
            // buffer pop + push scans
            float sbv = (lane < Ss) ? s_sb[elw * Ss + lane] : 0.0f;
            float Pb = wave_iscan(sbv, lane);
            float wb = fminf(Pb, a_s) - fminf(Pb - sbv, a_s);
            float sbn = sbv - wb;
            float Pb2 = wave_iscan(sbn, lane);
            float wbe = fminf(Pb2, 1.0f) - fminf(Pb2 - sbn, 1.0f);
            if (lane < Ss) {
                s_sb[elw * Ss + lane] = sbn;
                s_wb[elw * Ss + lane] = wb;
                s_wbe[elw * Ss + lane] = wbe;
            }
            // fused V loop: r1/r2 (pop weights) AND x1/x2 (push weights) in one pass
            const int mA = ms * 49;
            float a1 = 0.0f, a2 = 0.0f, x1 = 0.0f, x2 = 0.0f;
            #pragma unroll 7
            for (int k2 = 0; k2 < 49; k2++) {
                int m = mA + k2;
                float vv = Vg[m * 64 + elw * 16 + dl];
                float u1 = sw1[elw * 208 + m], u2 = sw2[elw * 208 + m];
                float p1 = pw1[elw * 208 + m], p2 = pw2[elw * 208 + m];
                a1 = fmaf(u1, vv, a1); a2 = fmaf(u2, vv, a2);
                x1 = fmaf(p1, vv, x1); x2 = fmaf(p2, vv, x2);
            }
            // buf (V[idx2]) and xb dots from LDS B
            float abf = 0.0f, axb = 0.0f;
            #pragma unroll
            for (int j = 0; j < 12; j++) {
                int s = ms * 12 + j;
                float be = s_B[(elw * Ss + s) * 17 + dl];
                abf = fmaf(s_wb[elw * Ss + s], be, abf);
                axb = fmaf(s_wbe[elw * Ss + s], be, axb);
            }
            abf = wred_ms(abf); axb = wred_ms(axb);
            if (lane < 16) Vg[idx2 * 64 + elw * 16 + dl] = abf;
            if (ms == 0) {
                x1 = fmaf(s_wx[elw * 4 + 2], abf, x1);
                x2 = fmaf(s_wx[elw * 4 + 3], abf, x2);
            }
            a1 = wred_ms(a1); a2 = wred_ms(a2);
            x1 = wred_ms(x1); x2 = wred_ms(x2);
            if (lane < 16) {
                st_co(R1g + (size_t)e * Hh + db + dl, a1);
                st_co(R2g + (size_t)e * Hh + db + dl, a2);
                s_xp1[elw * 16 + dl] = x1;
                s_xp2[elw * 16 + dl] = x2;
                s_xpb[elw * 16 + dl] = axb;
            }
        }
        gbar(cnt, ++barnum * 16);

        // ---------- Phase T2: tree cell (wave-per-row) + finish xt ----------
        {
            const int e = e0 + elw;
            vf4 r1v, r2v;
            ld_co_v4_2((const vf4*)R1g + (size_t)e * 64 + lane,
                       (const vf4*)R2g + (size_t)e * 64 + lane, r1v, r2v);
            #pragma unroll 4
            for (int r = 0; r < 80; r++) {
                int row = ((r >> 4) << 8) + db + (r & 15);   // g*256 + db + d, g<5
                const vf4* wl = (const vf4*)tlw + (size_t)row * 64;
                const vf4* wr = (const vf4*)trw + (size_t)row * 64;
                vf4 u = wl[lane], v = wr[lane];
                vf4 acc = {0.f, 0.f, 0.f, 0.f};
                FMA4(acc, u, r1v); FMA4(acc, v, r2v);
                float sv = wred64(acc.x + acc.y + acc.z + acc.w);
                if (lane == 0) s_tg[elw * 80 + r] = sv + s_tbias[r];
            }
            __syncthreads();
            if (tid < 64) {
                int el2 = tid >> 4, d2 = tid & 15;
                int e2 = e0 + el2;
                float ta  = s_tg[el2 * 80 + d2];
                float ti  = s_tg[el2 * 80 + 16 + d2];
                float tf1 = s_tg[el2 * 80 + 32 + d2];
                float tf2 = s_tg[el2 * 80 + 48 + d2];
                float to  = s_tg[el2 * 80 + 64 + d2];
                float r1d, r2d;
                ld_co_f2(R1g + (size_t)e2 * Hh + db + d2,
                         R2g + (size_t)e2 * Hh + db + d2, r1d, r2d);
                float ct = tanhf(ta) * sigf(ti) + sigf(tf1) * r1d + sigf(tf2) * r2d;
                float ht = sigf(to) * tanhf(ct);
                Vg[idx * 64 + el2 * 16 + d2] = ht;
                float x1f = fmaf(s_wx[el2 * 4 + 0], ht, s_xp1[tid]);
                float x2f = fmaf(s_wx[el2 * 4 + 1], ht, s_xp2[tid]);
                float* xte = XTg + (size_t)e2 * H3;
                st_co(xte + db + d2, s_xpb[tid]);
                st_co(xte + 256 + db + d2, x1f);
                st_co(xte + 512 + db + d2, x2f);
            }
        }
        gbar(cnt, ++barnum * 16);
    }

    // ================= MLP head =================
    {   // layer 0: input = XT[:, 256:512], wave-per-row
        const int e = e0 + elw;
        vf4 xin;
        ld_co_v4_1((const vf4*)XTg + (size_t)e * 192 + 64 + lane, xin);
        #pragma unroll 4
        for (int r = 0; r < 64; r++) {
            int row = q * 64 + r;
            const vf4* w = (const vf4*)l0w + (size_t)row * 64;
            vf4 wv = w[lane];
            vf4 acc = {0.f, 0.f, 0.f, 0.f};
            FMA4(acc, wv, xin);
            float sv = wred64(acc.x + acc.y + acc.z + acc.w);
            if (lane == 0) st_co(Y0g + (size_t)e * MLPD + row, fmaxf(sv + l0b[row], 0.0f));
        }
    }
    gbar(cnt, ++barnum * 16);
    {   // layer 1, wave-per-row (K=1024)
        const int e = e0 + elw;
        const vf4* yb = (const vf4*)Y0g + (size_t)e * 256;
        vf4 y0, y1, y2, y3;
        ld_co_v4_4(yb + lane, yb + 64 + lane, yb + 128 + lane, yb + 192 + lane, y0, y1, y2, y3);
        #pragma unroll 2
        for (int r = 0; r < 64; r++) {
            int row = q * 64 + r;
            const vf4* w = (const vf4*)l1w + (size_t)row * 256;
            vf4 w0 = w[lane], w1 = w[64 + lane], w2 = w[128 + lane], w3 = w[192 + lane];
            vf4 acc = {0.f, 0.f, 0.f, 0.f};
            FMA4(acc, w0, y0); FMA4(acc, w1, y1); FMA4(acc, w2, y2); FMA4(acc, w3, y3);
            float sv = wred64(acc.x + acc.y + acc.z + acc.w);
            if (lane == 0) st_co(Y1g + (size_t)e * MLPD + row, fmaxf(sv + l1b[row], 0.0f));
        }
    }
    gbar(cnt, ++barnum * 16);
    if (q < 4) {  // layer 2: block (eg, q=el) handles element e0+q
        int e = e0 + q;
        const vf4* p = (const vf4*)Y1g + (size_t)e * 256 + tid;
        vf4 yv;
        ld_co_v4_1(p, yv);
        #pragma unroll
        for (int r = 0; r < 3; r++) {
            const float* w = l2w + (size_t)r * MLPD + tid * 4;
            s_h[r * 256 + tid] = yv.x * w[0] + yv.y * w[1] + yv.z * w[2] + yv.w * w[3];
        }
        __syncthreads();
        for (int off = 128; off >= 1; off >>= 1) {
            if (tid < off) {
                #pragma unroll
                for (int r = 0; r < 3; r++)
                    s_h[r * 256 + tid] += s_h[r * 256 + tid + off];
            }
            __syncthreads();
        }
        if (tid < 3) out[e * 3 + tid] = s_h[tid * 256] + l2b[tid];
    }
}

extern "C" void kernel_launch(void* const* d_in, const int* in_sizes, int n_in,
                              void* d_out, int out_size, void* d_ws, size_t ws_size,
                              hipStream_t stream) {
    (void)in_sizes; (void)n_in; (void)out_size; (void)ws_size;
    (void)hipMemsetAsync(d_ws, 0, 4096, stream);  // per-group barrier counters

    const int*   x_   = (const int*)d_in[0];
    const float* emb  = (const float*)d_in[1];
    const float* wih  = (const float*)d_in[2];
    const float* whh  = (const float*)d_in[3];
    const float* bih  = (const float*)d_in[4];
    const float* bhh  = (const float*)d_in[5];
    const float* aw   = (const float*)d_in[6];
    const float* ab   = (const float*)d_in[7];
    const float* tlw  = (const float*)d_in[8];
    const float* tlb  = (const float*)d_in[9];
    const float* trw  = (const float*)d_in[10];
    const float* trb  = (const float*)d_in[11];
    const float* l0w  = (const float*)d_in[12];
    const float* l0b  = (const float*)d_in[13];
    const float* l1w  = (const float*)d_in[14];
    const float* l1b  = (const float*)d_in[15];
    const float* l2w  = (const float*)d_in[16];
    const float* l2b  = (const float*)d_in[17];

    float* wsf = (float*)((char*)d_ws + 4096);
    unsigned* bar = (unsigned*)d_ws;

    spinn_kernel<<<dim3(NBLK), dim3(NTHR), 0, stream>>>(
        x_, emb, wih, whh, bih, bhh, aw, ab, tlw, tlb, trw, trb,
        l0w, l0b, l1w, l1b, l2w, l2b, (float*)d_out, wsf, bar);
}

// Round 5
// 4077.507 us; speedup vs baseline: 1.9138x; 1.6634x over previous
//
#include <hip/hip_runtime.h>
#include <math.h>

#define NBLK 512
#define NTHR 256

typedef float vf4 __attribute__((ext_vector_type(4)));

namespace spinn {

constexpr int Bb = 64, Ss = 48, Hh = 256, TT = 96, Mm = 193, H3 = 768, MLPD = 1024;
constexpr int Mp = 196;   // padded stack rows (4 ms-groups x 49)
constexpr int EPG = 2;    // elements per group (2 -> 512 blocks -> 2 blocks/CU)

__device__ __forceinline__ float sigf(float x) { return 1.0f / (1.0f + expf(-x)); }

#define FMA4(acc, a, b)                         \
    {                                           \
        acc.x = fmaf((a).x, (b).x, acc.x);      \
        acc.y = fmaf((a).y, (b).y, acc.y);      \
        acc.z = fmaf((a).z, (b).z, acc.z);      \
        acc.w = fmaf((a).w, (b).w, acc.w);      \
    }

// ---- coherent (device-scope) access helpers ----
__device__ __forceinline__ void st_co(float* p, float v) {
    asm volatile("global_store_dword %0, %1, off sc0 sc1" :: "v"(p), "v"(v) : "memory");
}
__device__ __forceinline__ void ld_co_v4_1(const vf4* p0, vf4& r0) {
    asm volatile("global_load_dwordx4 %0, %1, off sc0 sc1\n\t"
                 "s_waitcnt vmcnt(0)"
                 : "=&v"(r0) : "v"(p0) : "memory");
}
__device__ __forceinline__ void ld_co_v4_2(const vf4* p0, const vf4* p1, vf4& r0, vf4& r1) {
    asm volatile("global_load_dwordx4 %0, %2, off sc0 sc1\n\t"
                 "global_load_dwordx4 %1, %3, off sc0 sc1\n\t"
                 "s_waitcnt vmcnt(0)"
                 : "=&v"(r0), "=&v"(r1) : "v"(p0), "v"(p1) : "memory");
}
__device__ __forceinline__ void ld_co_v4_3(const vf4* p0, const vf4* p1, const vf4* p2,
                                           vf4& r0, vf4& r1, vf4& r2) {
    asm volatile("global_load_dwordx4 %0, %3, off sc0 sc1\n\t"
                 "global_load_dwordx4 %1, %4, off sc0 sc1\n\t"
                 "global_load_dwordx4 %2, %5, off sc0 sc1\n\t"
                 "s_waitcnt vmcnt(0)"
                 : "=&v"(r0), "=&v"(r1), "=&v"(r2) : "v"(p0), "v"(p1), "v"(p2) : "memory");
}
__device__ __forceinline__ void ld_co_v4_4(const vf4* p0, const vf4* p1, const vf4* p2, const vf4* p3,
                                           vf4& r0, vf4& r1, vf4& r2, vf4& r3) {
    asm volatile("global_load_dwordx4 %0, %4, off sc0 sc1\n\t"
                 "global_load_dwordx4 %1, %5, off sc0 sc1\n\t"
                 "global_load_dwordx4 %2, %6, off sc0 sc1\n\t"
                 "global_load_dwordx4 %3, %7, off sc0 sc1\n\t"
                 "s_waitcnt vmcnt(0)"
                 : "=&v"(r0), "=&v"(r1), "=&v"(r2), "=&v"(r3)
                 : "v"(p0), "v"(p1), "v"(p2), "v"(p3) : "memory");
}
__device__ __forceinline__ void ld_co_f1x4(const float* p0, const float* p1, const float* p2,
                                           const float* p3, float& r0, float& r1, float& r2, float& r3) {
    asm volatile("global_load_dword %0, %4, off sc0 sc1\n\t"
                 "global_load_dword %1, %5, off sc0 sc1\n\t"
                 "global_load_dword %2, %6, off sc0 sc1\n\t"
                 "global_load_dword %3, %7, off sc0 sc1\n\t"
                 "s_waitcnt vmcnt(0)"
                 : "=&v"(r0), "=&v"(r1), "=&v"(r2), "=&v"(r3)
                 : "v"(p0), "v"(p1), "v"(p2), "v"(p3) : "memory");
}
__device__ __forceinline__ unsigned ld_co_u32(const unsigned* p) {
    unsigned r;
    asm volatile("global_load_dword %0, %1, off sc0 sc1\n\t"
                 "s_waitcnt vmcnt(0)"
                 : "=&v"(r) : "v"(p) : "memory");
    return r;
}

// ---- per-group (16-block) barrier ----
__device__ __forceinline__ void gbar(unsigned* cnt, unsigned tgt) {
    asm volatile("s_waitcnt vmcnt(0)" ::: "memory");
    __syncthreads();
    if (threadIdx.x == 0) {
        unsigned one = 1u;
        asm volatile("global_atomic_add %0, %1, off" :: "v"(cnt), "v"(one) : "memory");
        while (ld_co_u32(cnt) < tgt) __builtin_amdgcn_s_sleep(1);
    }
    __syncthreads();
}

// ---- wave-level (64-lane) primitives ----
__device__ __forceinline__ float wave_iscan(float v, int lane) {
    #pragma unroll
    for (int off = 1; off < 64; off <<= 1) {
        float u = __shfl_up(v, off, 64);
        if (lane >= off) v += u;
    }
    return v;
}
__device__ __forceinline__ float wred64(float v) {
    #pragma unroll
    for (int off = 1; off < 64; off <<= 1) v += __shfl_xor(v, off, 64);
    return v;
}
__device__ __forceinline__ float wred_ms(float v) {  // reduce over lane bits 4,5
    v += __shfl_xor(v, 16, 64);
    v += __shfl_xor(v, 32, 64);
    return v;
}

}  // namespace spinn

using namespace spinn;

__global__ void __launch_bounds__(NTHR, 2) spinn_kernel(
    const int* __restrict__ x, const float* __restrict__ emb,
    const float* __restrict__ wih, const float* __restrict__ whh,
    const float* __restrict__ bih, const float* __restrict__ bhh,
    const float* __restrict__ aw, const float* __restrict__ ab,
    const float* __restrict__ tlw, const float* __restrict__ tlb,
    const float* __restrict__ trw, const float* __restrict__ trb,
    const float* __restrict__ l0w, const float* __restrict__ l0b,
    const float* __restrict__ l1w, const float* __restrict__ l1b,
    const float* __restrict__ l2w, const float* __restrict__ l2b,
    float* __restrict__ out, float* __restrict__ wsf, unsigned* __restrict__ bar)
{
    const int tid = threadIdx.x;
    const int bid = blockIdx.x;
    const int eg = bid >> 4;          // element group (2 elements), 0..31
    const int q  = bid & 15;          // dim slice (16 dims)
    const int e0 = eg * EPG;
    const int db = q * 16;

    unsigned* cnt = bar + eg * 32;    // per-group counter, 128B apart
    unsigned barnum = 0;

    // ---- global workspace (floats) ----
    float* XTg  = wsf;                          // [64][768]
    float* Hbg  = XTg + 64 * H3;                // [64][256]
    float* R1g  = Hbg + 64 * Hh;                // [64][256]
    float* R2g  = R1g + 64 * Hh;                // [64][256]
    float* Y0g  = R2g + 64 * Hh;                // [64][1024]
    float* Y1g  = Y0g + 64 * MLPD;              // [64][1024]
    float* Vall = Y1g + 64 * MLPD;
    float* Vg   = Vall + (size_t)bid * (Mp * 32);  // private [196][2 el][16 d]

    // ---- LDS ----
    __shared__ float s_xt[1536];     // union: [2][768] xt staging | [2][256]x2 r1/r2 staging
    __shared__ float s_h[512];       // [2][256] h_t
    __shared__ float s_c[32];        // [2][16]
    __shared__ float s_g[128];       // [2][4 gates][16]
    __shared__ float s_tg[160];      // [2][5 gates][16]
    __shared__ float s_s[416];       // [2][208] stack strengths (padded); waves 0,1 only
    __shared__ float s_sb[96];       // [2][48]; waves 2,3 only (after init)
    __shared__ float sw1[416], sw2[416];   // pop weights  (written by waves 0,1)
    __shared__ float pw1[416], pw2[416];   // push weights (written by waves 0,1)
    __shared__ float s_wb[96], s_wbe[96];  // buffer weights (written by waves 2,3)
    __shared__ float s_wx[8];        // [2][4]
    __shared__ float s_xp1[32], s_xp2[32], s_xpb[32];
    __shared__ float s_bias[64];     // bih+bhh for this q's 64 LSTM rows
    __shared__ float s_tbias[80];    // tlb+trb for this q's 80 tree rows
    __shared__ float s_B[EPG * Ss * 17]; // [2 el][48][16+pad]; reused by MLP L2 reduce

    const int lane = tid & 63;
    const int elw  = tid >> 6;       // wave id 0..3
    const int el   = elw & 1;        // element within group (waves 0,2 -> el0; 1,3 -> el1)
    const int rh   = elw >> 1;       // row-half for matvec phases
    const int ms   = lane >> 4;
    const int dl   = lane & 15;

    // ================= INIT =================
    {
        for (int i = tid; i < EPG * Ss * 16; i += NTHR) {
            int ee = i / (Ss * 16);
            int rem = i - ee * (Ss * 16);
            int s = rem >> 4, d = rem & 15;
            int tok = x[(e0 + ee) * Ss + s];
            s_B[(ee * Ss + s) * 17 + d] = emb[(size_t)tok * Hh + db + d];
        }
        if (tid < EPG * Ss) {
            int ee = tid / Ss, s = tid % Ss;
            s_sb[tid] = (x[(e0 + ee) * Ss + s] > 0) ? 1.0f : 0.0f;
        }
        for (int i = tid; i < 416; i += NTHR) s_s[i] = 0.0f;
        for (int i = tid; i < 512; i += NTHR) s_h[i] = 0.0f;
        if (tid < 32) s_c[tid] = 0.0f;
        if (tid < 64) {
            int row = (tid >> 4) * Hh + db + (tid & 15);
            s_bias[tid] = bih[row] + bhh[row];
        }
        if (tid < 80) {
            int row = (tid >> 4) * Hh + db + (tid & 15);
            s_tbias[tid] = tlb[row] + trb[row];
        }
        for (int i = tid; i < Mp * 32; i += NTHR) Vg[i] = 0.0f;
        asm volatile("s_waitcnt vmcnt(0)" ::: "memory");
        __syncthreads();
        // initial x_b = read_buffer(ones); x1 = x2 = 0  (waves 0,1 only: avoids
        // any twin read/write overlap on s_wbe)
        if (elw < 2) {
            float sbv = (lane < Ss) ? s_sb[el * Ss + lane] : 0.0f;
            float P = wave_iscan(sbv, lane);
            float wbe = fminf(P, 1.0f) - fminf(P - sbv, 1.0f);
            if (lane < Ss) s_wbe[el * Ss + lane] = wbe;
            float axb = 0.0f;
            #pragma unroll
            for (int j = 0; j < 12; j++) {
                int s = ms * 12 + j;
                axb = fmaf(s_wbe[el * Ss + s], s_B[(el * Ss + s) * 17 + dl], axb);
            }
            axb = wred_ms(axb);
            if (lane < 16) {
                float* xte = XTg + (size_t)(e0 + el) * H3;
                st_co(xte + db + dl, axb);
                st_co(xte + 256 + db + dl, 0.0f);
                st_co(xte + 512 + db + dl, 0.0f);
            }
        }
    }
    gbar(cnt, ++barnum * 16);

    // ================= time loop =================
    for (int t = 0; t < TT; t++) {
        const int idx  = 191 - 2 * t;
        const int idx2 = idx - 1;

        // ---------- Phase L: LSTM (wave-per-row coalesced dots) ----------
        {
            // waves 0,1 stage xt[el] coherently into LDS; all waves consume
            if (elw < 2) {
                const vf4* src = (const vf4*)XTg + (size_t)(e0 + el) * 192;
                vf4 a, b, c;
                ld_co_v4_3(src + lane, src + 64 + lane, src + 128 + lane, a, b, c);
                vf4* sx = (vf4*)s_xt;
                sx[el * 192 + lane] = a;
                sx[el * 192 + 64 + lane] = b;
                sx[el * 192 + 128 + lane] = c;
            }
            __syncthreads();
            vf4 xr0 = ((const vf4*)s_xt)[el * 192 + lane];
            vf4 xr1 = ((const vf4*)s_xt)[el * 192 + 64 + lane];
            vf4 xr2 = ((const vf4*)s_xt)[el * 192 + 128 + lane];
            vf4 hr  = ((const vf4*)s_h)[el * 64 + lane];
            #pragma unroll 4
            for (int r = rh * 32; r < rh * 32 + 32; r++) {
                int row = ((r >> 4) << 8) + db + (r & 15);   // g*256 + db + d
                const vf4* w  = (const vf4*)wih + (size_t)row * 192;
                const vf4* wh = (const vf4*)whh + (size_t)row * 64;
                vf4 w0 = w[lane], w1 = w[64 + lane], w2 = w[128 + lane], w3 = wh[lane];
                vf4 acc = {0.f, 0.f, 0.f, 0.f};
                FMA4(acc, w0, xr0); FMA4(acc, w1, xr1);
                FMA4(acc, w2, xr2); FMA4(acc, w3, hr);
                float sv = wred64(acc.x + acc.y + acc.z + acc.w);
                if (lane == 0) s_g[el * 64 + r] = sv + s_bias[r];
            }
            __syncthreads();
            if (tid < 32) {
                int el2 = tid >> 4, d2 = tid & 15;
                float gi = s_g[el2 * 64 + d2], gf = s_g[el2 * 64 + 16 + d2];
                float gg = s_g[el2 * 64 + 32 + d2], go = s_g[el2 * 64 + 48 + d2];
                float cv = sigf(gf) * s_c[tid] + sigf(gi) * tanhf(gg);
                s_c[tid] = cv;
                float hv = sigf(go) * tanhf(cv);
                st_co(Hbg + (size_t)(e0 + el2) * Hh + db + d2, hv);
            }
        }
        gbar(cnt, ++barnum * 16);

        // ---------- Phase T1 (scan ownership: waves 0,1 = stack; 2,3 = buffer) ----------
        {
            // waves 0,1 stage full h into LDS; all waves consume
            if (elw < 2) {
                float h0, h1, h2, h3;
                const float* hb = Hbg + (size_t)(e0 + el) * Hh + lane;
                ld_co_f1x4(hb, hb + 64, hb + 128, hb + 192, h0, h1, h2, h3);
                s_h[el * Hh + lane] = h0;       s_h[el * Hh + 64 + lane] = h1;
                s_h[el * Hh + 128 + lane] = h2; s_h[el * Hh + 192 + lane] = h3;
            }
            __syncthreads();
            float h0 = s_h[el * Hh + lane],       h1 = s_h[el * Hh + 64 + lane];
            float h2 = s_h[el * Hh + 128 + lane], h3 = s_h[el * Hh + 192 + lane];
            float lg0 = h0 * aw[lane] + h1 * aw[64 + lane] + h2 * aw[128 + lane] + h3 * aw[192 + lane];
            float lg1 = h0 * aw[256 + lane] + h1 * aw[320 + lane] + h2 * aw[384 + lane] + h3 * aw[448 + lane];
            lg0 = wred64(lg0) + ab[0];
            lg1 = wred64(lg1) + ab[1];
            float a_r = 1.0f / (1.0f + expf(10.0f * (lg1 - lg0)));
            float a_s = 1.0f / (1.0f + expf(10.0f * (lg0 - lg1)));

            if (elw < 2) {
                // ----- STACK scans (sole owner of s_s / sw / pw / s_wx) -----
                int m0 = lane * 4;
                float v0 = (m0     < Mm) ? s_s[el * 208 + m0]     : 0.0f;
                float v1 = (m0 + 1 < Mm) ? s_s[el * 208 + m0 + 1] : 0.0f;
                float v2 = (m0 + 2 < Mm) ? s_s[el * 208 + m0 + 2] : 0.0f;
                float v3 = (m0 + 3 < Mm) ? s_s[el * 208 + m0 + 3] : 0.0f;
                float c1 = v0 + v1, c2 = c1 + v2, c3 = c2 + v3;
                float inc = c3;
                #pragma unroll
                for (int off = 1; off < 64; off <<= 1) {
                    float u = __shfl_up(inc, off, 64);
                    if (lane >= off) inc += u;
                }
                float ex = inc - c3;
                float Pv[4]  = {ex + v0, ex + c1, ex + c2, ex + c3};
                float Pp[4]  = {ex, ex + v0, ex + c1, ex + c2};
                float vv_[4] = {v0, v1, v2, v3};
                float sn[4];
                #pragma unroll
                for (int i = 0; i < 4; i++) {
                    int m = m0 + i;
                    float w1 = fminf(Pv[i], a_r) - fminf(Pp[i], a_r);
                    float wt = fminf(Pv[i], 1.0f + a_r) - fminf(Pp[i], 1.0f + a_r);
                    float s2 = vv_[i] - wt;
                    if (m == idx) s2 = a_r;
                    if (m == idx2) s2 = a_s;
                    sn[i] = s2;
                    if (m < Mm) {
                        sw1[el * 208 + m] = w1;
                        sw2[el * 208 + m] = wt - w1;
                        s_s[el * 208 + m] = s2;
                    } else if (m < Mp) {
                        sw1[el * 208 + m] = 0.0f;
                        sw2[el * 208 + m] = 0.0f;
                    }
                }
                // push scan (alpha = 1) on updated s
                float d1 = sn[0] + sn[1], d2 = d1 + sn[2], d3 = d2 + sn[3];
                float inc2 = d3;
                #pragma unroll
                for (int off = 1; off < 64; off <<= 1) {
                    float u = __shfl_up(inc2, off, 64);
                    if (lane >= off) inc2 += u;
                }
                float ex2 = inc2 - d3;
                float Qv[4] = {ex2 + sn[0], ex2 + d1, ex2 + d2, ex2 + d3};
                float Qp[4] = {ex2, ex2 + sn[0], ex2 + d1, ex2 + d2};
                #pragma unroll
                for (int i = 0; i < 4; i++) {
                    int m = m0 + i;
                    float w1e = fminf(Qv[i], 1.0f) - fminf(Qp[i], 1.0f);
                    float w2e = (fminf(Qv[i], 2.0f) - fminf(Qp[i], 2.0f)) - w1e;
                    if (m == idx)  { s_wx[el * 4 + 0] = w1e; s_wx[el * 4 + 1] = w2e; w1e = 0.0f; w2e = 0.0f; }
                    if (m == idx2) { s_wx[el * 4 + 2] = w1e; s_wx[el * 4 + 3] = w2e; w1e = 0.0f; w2e = 0.0f; }
                    if (m < Mm) {
                        pw1[el * 208 + m] = w1e;
                        pw2[el * 208 + m] = w2e;
                    } else if (m < Mp) {
                        pw1[el * 208 + m] = 0.0f;
                        pw2[el * 208 + m] = 0.0f;
                    }
                }
            } else {
                // ----- BUFFER scans (sole owner of s_sb / s_wb / s_wbe) -----
                float sbv = (lane < Ss) ? s_sb[el * Ss + lane] : 0.0f;
                float Pb = wave_iscan(sbv, lane);
                float wb = fminf(Pb, a_s) - fminf(Pb - sbv, a_s);
                float sbn = sbv - wb;
                float Pb2 = wave_iscan(sbn, lane);
                float wbe = fminf(Pb2, 1.0f) - fminf(Pb2 - sbn, 1.0f);
                if (lane < Ss) {
                    s_sb[el * Ss + lane] = sbn;
                    s_wb[el * Ss + lane] = wb;
                    s_wbe[el * Ss + lane] = wbe;
                }
            }
            __syncthreads();
            if (elw < 2) {
                // fused V loop: r1/r2 (pop weights) AND x1/x2 (push weights)
                const int mA = ms * 49;
                float a1 = 0.0f, a2 = 0.0f, x1 = 0.0f, x2 = 0.0f;
                #pragma unroll 7
                for (int k2 = 0; k2 < 49; k2++) {
                    int m = mA + k2;
                    float vv = Vg[m * 32 + el * 16 + dl];
                    float u1 = sw1[el * 208 + m], u2 = sw2[el * 208 + m];
                    float p1 = pw1[el * 208 + m], p2 = pw2[el * 208 + m];
                    a1 = fmaf(u1, vv, a1); a2 = fmaf(u2, vv, a2);
                    x1 = fmaf(p1, vv, x1); x2 = fmaf(p2, vv, x2);
                }
                // buf (V[idx2]) and xb dots from LDS B
                float abf = 0.0f, axb = 0.0f;
                #pragma unroll
                for (int j = 0; j < 12; j++) {
                    int s = ms * 12 + j;
                    float be = s_B[(el * Ss + s) * 17 + dl];
                    abf = fmaf(s_wb[el * Ss + s], be, abf);
                    axb = fmaf(s_wbe[el * Ss + s], be, axb);
                }
                abf = wred_ms(abf); axb = wred_ms(axb);
                if (lane < 16) Vg[idx2 * 32 + el * 16 + dl] = abf;
                if (ms == 0) {
                    x1 = fmaf(s_wx[el * 4 + 2], abf, x1);
                    x2 = fmaf(s_wx[el * 4 + 3], abf, x2);
                }
                a1 = wred_ms(a1); a2 = wred_ms(a2);
                x1 = wred_ms(x1); x2 = wred_ms(x2);
                if (lane < 16) {
                    st_co(R1g + (size_t)(e0 + el) * Hh + db + dl, a1);
                    st_co(R2g + (size_t)(e0 + el) * Hh + db + dl, a2);
                    s_xp1[el * 16 + dl] = x1;
                    s_xp2[el * 16 + dl] = x2;
                    s_xpb[el * 16 + dl] = axb;
                }
            }
        }
        gbar(cnt, ++barnum * 16);

        // ---------- Phase T2: tree cell (wave-per-row) + finish xt ----------
        {
            // waves 0,1 stage full R1/R2 into LDS (s_xt reuse); all consume
            if (elw < 2) {
                vf4 r1v, r2v;
                ld_co_v4_2((const vf4*)R1g + (size_t)(e0 + el) * 64 + lane,
                           (const vf4*)R2g + (size_t)(e0 + el) * 64 + lane, r1v, r2v);
                ((vf4*)s_xt)[el * 64 + lane] = r1v;
                ((vf4*)s_xt)[128 + el * 64 + lane] = r2v;
            }
            __syncthreads();
            vf4 r1v = ((const vf4*)s_xt)[el * 64 + lane];
            vf4 r2v = ((const vf4*)s_xt)[128 + el * 64 + lane];
            #pragma unroll 4
            for (int r = rh * 40; r < rh * 40 + 40; r++) {
                int row = ((r >> 4) << 8) + db + (r & 15);   // g*256 + db + d, g<5
                const vf4* wl = (const vf4*)tlw + (size_t)row * 64;
                const vf4* wr = (const vf4*)trw + (size_t)row * 64;
                vf4 u = wl[lane], v = wr[lane];
                vf4 acc = {0.f, 0.f, 0.f, 0.f};
                FMA4(acc, u, r1v); FMA4(acc, v, r2v);
                float sv = wred64(acc.x + acc.y + acc.z + acc.w);
                if (lane == 0) s_tg[el * 80 + r] = sv + s_tbias[r];
            }
            __syncthreads();
            if (tid < 32) {
                int el2 = tid >> 4, d2 = tid & 15;
                int e2 = e0 + el2;
                float ta  = s_tg[el2 * 80 + d2];
                float ti  = s_tg[el2 * 80 + 16 + d2];
                float tf1 = s_tg[el2 * 80 + 32 + d2];
                float tf2 = s_tg[el2 * 80 + 48 + d2];
                float to  = s_tg[el2 * 80 + 64 + d2];
                float r1d = s_xt[el2 * 256 + db + d2];
                float r2d = s_xt[512 + el2 * 256 + db + d2];
                float ct = tanhf(ta) * sigf(ti) + sigf(tf1) * r1d + sigf(tf2) * r2d;
                float ht = sigf(to) * tanhf(ct);
                Vg[idx * 32 + el2 * 16 + d2] = ht;
                float x1f = fmaf(s_wx[el2 * 4 + 0], ht, s_xp1[tid]);
                float x2f = fmaf(s_wx[el2 * 4 + 1], ht, s_xp2[tid]);
                float* xte = XTg + (size_t)e2 * H3;
                st_co(xte + db + d2, s_xpb[tid]);
                st_co(xte + 256 + db + d2, x1f);
                st_co(xte + 512 + db + d2, x2f);
            }
        }
        gbar(cnt, ++barnum * 16);
    }

    // ================= MLP head =================
    {   // layer 0: input = XT[:, 256:512], wave-per-row (rows split by rh)
        vf4 xin;
        ld_co_v4_1((const vf4*)XTg + (size_t)(e0 + el) * 192 + 64 + lane, xin);
        #pragma unroll 4
        for (int r = rh * 32; r < rh * 32 + 32; r++) {
            int row = q * 64 + r;
            const vf4* w = (const vf4*)l0w + (size_t)row * 64;
            vf4 wv = w[lane];
            vf4 acc = {0.f, 0.f, 0.f, 0.f};
            FMA4(acc, wv, xin);
            float sv = wred64(acc.x + acc.y + acc.z + acc.w);
            if (lane == 0) st_co(Y0g + (size_t)(e0 + el) * MLPD + row, fmaxf(sv + l0b[row], 0.0f));
        }
    }
    gbar(cnt, ++barnum * 16);
    {   // layer 1, wave-per-row (K=1024)
        const vf4* yb = (const vf4*)Y0g + (size_t)(e0 + el) * 256;
        vf4 y0, y1, y2, y3;
        ld_co_v4_4(yb + lane, yb + 64 + lane, yb + 128 + lane, yb + 192 + lane, y0, y1, y2, y3);
        #pragma unroll 2
        for (int r = rh * 32; r < rh * 32 + 32; r++) {
            int row = q * 64 + r;
            const vf4* w = (const vf4*)l1w + (size_t)row * 256;
            vf4 w0 = w[lane], w1 = w[64 + lane], w2 = w[128 + lane], w3 = w[192 + lane];
            vf4 acc = {0.f, 0.f, 0.f, 0.f};
            FMA4(acc, w0, y0); FMA4(acc, w1, y1); FMA4(acc, w2, y2); FMA4(acc, w3, y3);
            float sv = wred64(acc.x + acc.y + acc.z + acc.w);
            if (lane == 0) st_co(Y1g + (size_t)(e0 + el) * MLPD + row, fmaxf(sv + l1b[row], 0.0f));
        }
    }
    gbar(cnt, ++barnum * 16);
    if (q < EPG) {  // layer 2: block (eg, q=el) handles element e0+q
        int e = e0 + q;
        const vf4* p = (const vf4*)Y1g + (size_t)e * 256 + tid;
        vf4 yv;
        ld_co_v4_1(p, yv);
        float* red = s_B;   // reuse [>=768]
        #pragma unroll
        for (int r = 0; r < 3; r++) {
            const float* w = l2w + (size_t)r * MLPD + tid * 4;
            red[r * 256 + tid] = yv.x * w[0] + yv.y * w[1] + yv.z * w[2] + yv.w * w[3];
        }
        __syncthreads();
        for (int off = 128; off >= 1; off >>= 1) {
            if (tid < off) {
                #pragma unroll
                for (int r = 0; r < 3; r++)
                    red[r * 256 + tid] += red[r * 256 + tid + off];
            }
            __syncthreads();
        }
        if (tid < 3) out[e * 3 + tid] = red[tid * 256] + l2b[tid];
    }
}

extern "C" void kernel_launch(void* const* d_in, const int* in_sizes, int n_in,
                              void* d_out, int out_size, void* d_ws, size_t ws_size,
                              hipStream_t stream) {
    (void)in_sizes; (void)n_in; (void)out_size; (void)ws_size;
    (void)hipMemsetAsync(d_ws, 0, 4096, stream);  // per-group barrier counters

    const int*   x_   = (const int*)d_in[0];
    const float* emb  = (const float*)d_in[1];
    const float* wih  = (const float*)d_in[2];
    const float* whh  = (const float*)d_in[3];
    const float* bih  = (const float*)d_in[4];
    const float* bhh  = (const float*)d_in[5];
    const float* aw   = (const float*)d_in[6];
    const float* ab   = (const float*)d_in[7];
    const float* tlw  = (const float*)d_in[8];
    const float* tlb  = (const float*)d_in[9];
    const float* trw  = (const float*)d_in[10];
    const float* trb  = (const float*)d_in[11];
    const float* l0w  = (const float*)d_in[12];
    const float* l0b  = (const float*)d_in[13];
    const float* l1w  = (const float*)d_in[14];
    const float* l1b  = (const float*)d_in[15];
    const float* l2w  = (const float*)d_in[16];
    const float* l2b  = (const float*)d_in[17];

    float* wsf = (float*)((char*)d_ws + 4096);
    unsigned* bar = (unsigned*)d_ws;

    spinn_kernel<<<dim3(NBLK), dim3(NTHR), 0, stream>>>(
        x_, emb, wih, whh, bih, bhh, aw, ab, tlw, tlb, trw, trb,
        l0w, l0b, l1w, l1b, l2w, l2b, (float*)d_out, wsf, bar);
}